// Round 10
// baseline (795.409 us; speedup 1.0000x reference)
//
#include <hip/hip_runtime.h>
#include <math.h>

#define C 512
#define K 256
#define HW 160
#define NPIX (HW*HW)   // 25600
#define PW 162
#define EPS 1e-5f

typedef __attribute__((ext_vector_type(8))) short s16x8;
typedef __attribute__((ext_vector_type(16))) float f32x16;

__device__ __forceinline__ unsigned short f2bf(float f) {
    unsigned int u = __float_as_uint(f);
    u += 0x7fffu + ((u >> 16) & 1u);
    return (unsigned short)(u >> 16);
}

// async global->LDS 16B: LDS dest = wave-uniform base + lane*16
__device__ __forceinline__ void ldg_lds16(const void* g, void* l) {
    __builtin_amdgcn_global_load_lds((const __attribute__((address_space(1))) unsigned int*)g,
                                     (__attribute__((address_space(3))) unsigned int*)l, 16, 0, 0);
}

#define WAIT_VM0()   asm volatile("s_waitcnt vmcnt(0)" ::: "memory")
#define WAIT_VM14()  asm volatile("s_waitcnt vmcnt(14)" ::: "memory")
#define WAIT_VM23()  asm volatile("s_waitcnt vmcnt(23)" ::: "memory")

// ---------------- per-channel mean & max ----------------
__global__ void reduce_kernel(const float* __restrict__ x,
                              float* __restrict__ avg, float* __restrict__ mx) {
    int c = blockIdx.x;
    const float4* xc = (const float4*)(x + (size_t)c * NPIX);
    float s = 0.f, m = -INFINITY;
    for (int p = threadIdx.x; p < NPIX / 4; p += 256) {
        float4 v = xc[p];
        s += v.x + v.y + v.z + v.w;
        m = fmaxf(m, fmaxf(fmaxf(v.x, v.y), fmaxf(v.z, v.w)));
    }
    __shared__ float ss[256], sm[256];
    ss[threadIdx.x] = s; sm[threadIdx.x] = m;
    __syncthreads();
    for (int o = 128; o > 0; o >>= 1) {
        if (threadIdx.x < o) {
            ss[threadIdx.x] += ss[threadIdx.x + o];
            sm[threadIdx.x] = fmaxf(sm[threadIdx.x], sm[threadIdx.x + o]);
        }
        __syncthreads();
    }
    if (threadIdx.x == 0) {
        avg[c] = ss[0] / (float)NPIX;
        mx[c]  = sm[0];
    }
}

// ---------------- MLP + sigmoid + top-K selection ----------------
__global__ void mlp_select_kernel(const float* __restrict__ avg,
                                  const float* __restrict__ mx,
                                  const float* __restrict__ w_fc1,
                                  const float* __restrict__ w_fc2,
                                  float* __restrict__ scales_out,
                                  int* __restrict__ idx,
                                  int* __restrict__ pos) {
    __shared__ float s_avg[C], s_mx[C], s_h[K], s_scales[C];
    __shared__ int s_sel[C];
    int t = threadIdx.x;
    s_avg[t] = avg[t];
    s_mx[t]  = mx[t];
    __syncthreads();
    if (t < K) {
        float ha = 0.f, hm = 0.f;
        const float4* wr = (const float4*)(w_fc1 + (size_t)t * C);
        for (int c = 0; c < C / 4; c++) {
            float4 w = wr[c];
            ha += s_avg[4*c]*w.x + s_avg[4*c+1]*w.y + s_avg[4*c+2]*w.z + s_avg[4*c+3]*w.w;
            hm += s_mx[4*c]*w.x + s_mx[4*c+1]*w.y + s_mx[4*c+2]*w.z + s_mx[4*c+3]*w.w;
        }
        s_h[t] = fmaxf(ha, 0.f) + fmaxf(hm, 0.f);
    }
    __syncthreads();
    {
        float o = 0.f;
        const float4* wr = (const float4*)(w_fc2 + (size_t)t * K);
        for (int k = 0; k < K / 4; k++) {
            float4 w = wr[k];
            o += s_h[4*k]*w.x + s_h[4*k+1]*w.y + s_h[4*k+2]*w.z + s_h[4*k+3]*w.w;
        }
        float sc = 1.f / (1.f + expf(-o));
        s_scales[t] = sc;
        scales_out[t] = sc;
    }
    __syncthreads();
    {
        float v = s_scales[t];
        int rank = 0;
        for (int i = 0; i < C; i++) {
            float u = s_scales[i];
            rank += (u > v) || (u == v && i < t);
        }
        s_sel[t] = (rank < K) ? 1 : 0;
    }
    __syncthreads();
    {
        int p = 0;
        for (int i = 0; i < t; i++) p += s_sel[i];
        if (s_sel[t]) { idx[p] = t; pos[t] = p; }
        else pos[t] = -1;
    }
}

// ---- fused prep: fragment-linear w3f + wAf repacks + zero border + affine ----
__global__ void prep_kernel(const float* __restrict__ w_dc2, unsigned short* __restrict__ w3f,
                            const float* __restrict__ w_dc1, const float* __restrict__ scales,
                            const int* __restrict__ pos, unsigned short* __restrict__ wAf,
                            unsigned short* __restrict__ hpad,
                            const float* __restrict__ b_dc1,
                            const float* __restrict__ g2, const float* __restrict__ b2,
                            const float* __restrict__ m2, const float* __restrict__ v2,
                            float* __restrict__ scale2, float* __restrict__ shift2) {
    int b = blockIdx.x;
    if (b < 384) {                       // w3f: fragment-linear conv3 weights
        int g = b / 48, ph = b % 48;
        int dy = ph >> 4, kc = ph & 15;
        for (int u = threadIdx.x; u < 6144; u += 256) {
            int chunk = u >> 9;                       // dx*4 + j*2 + s
            int dx = chunk >> 2, j = (chunk >> 1) & 1, s = chunk & 1;
            int r = u & 511, lane = r >> 3, e = r & 7;
            int co = g * 64 + j * 32 + (lane & 31);
            int qq = lane >> 5;
            int ci = kc * 32 + (s * 2 + qq) * 8 + e;
            w3f[(size_t)b * 6144 + u] = f2bf(w_dc2[((size_t)co * 512 + ci) * 9 + dy * 3 + dx]);
        }
    } else if (b < 576) {                // wAf: fragment-linear combined 1x1 weights
        int bb = b - 384;
        int g = bb / 24, ph = bb % 24;
        for (int u = threadIdx.x; u < 2048; u += 256) {
            int chunk = u >> 9;                       // j*2 + s
            int j = chunk >> 1, s = chunk & 1;
            int r = u & 511, lane = r >> 3, e = r & 7;
            int co = g * 64 + j * 32 + (lane & 31);
            int qq = lane >> 5;
            int c = ph * 32 + (s * 2 + qq) * 8 + e;
            const float* wr = w_dc1 + (size_t)co * 1024;
            float v;
            if (c < 512) {
                v = wr[c] * scales[c];
                int pp = pos[c];
                if (pp >= 0) v += wr[512 + pp];
            } else {
                v = wr[768 + (c - 512)];
            }
            wAf[(size_t)bb * 2048 + u] = f2bf(v);
        }
    } else if (b < 737) {                // zero hpad border
        int t = (b - 576) * 256 + threadIdx.x;
        int pix = t >> 6;
        int p;
        if (pix < 162)      p = pix;
        else if (pix < 324) p = 161 * PW + (pix - 162);
        else {
            int r = pix - 324;
            p = (1 + (r >> 1)) * PW + ((r & 1) ? 161 : 0);
        }
        *(uint4*)&hpad[(size_t)p * 512 + (t & 63) * 8] = make_uint4(0u, 0u, 0u, 0u);
    } else {                             // affine (BN2 + bias fold)
        for (int c = threadIdx.x; c < C; c += 256) {
            float s = g2[c] * rsqrtf(v2[c] + EPS);
            scale2[c] = s;
            shift2[c] = (b_dc1[c] - m2[c]) * s + b2[c];
        }
    }
}

// ---------------- dw 3x3 + BN1 + ReLU, written transposed into xcat[.,512+k] ----
__global__ void dw_t_kernel(const float* __restrict__ x,
                            const int* __restrict__ idx,
                            const float* __restrict__ wch,
                            const float* __restrict__ g1, const float* __restrict__ b1,
                            const float* __restrict__ m1, const float* __restrict__ v1,
                            unsigned short* __restrict__ xcat) {
    __shared__ float tile[32][33];
    int tx = threadIdx.x & 31, ty = threadIdx.x >> 5;
    int pbase = blockIdx.x * 32, kbase = blockIdx.y * 32;
    int y = pbase / HW, x0 = pbase % HW;
    int px = x0 + tx;
#pragma unroll
    for (int jj = 0; jj < 4; jj++) {
        int k = kbase + ty + jj * 8;
        int c = idx[k];
        const float* xc = x + (size_t)c * NPIX;
        const float* wk = wch + k * 9;
        float acc = 0.f;
#pragma unroll
        for (int dy = 0; dy < 3; dy++) {
            int yy = y + dy - 1;
            if (yy < 0 || yy >= HW) continue;
#pragma unroll
            for (int dx = 0; dx < 3; dx++) {
                int xv = px + dx - 1;
                if (xv < 0 || xv >= HW) continue;
                acc += xc[yy * HW + xv] * wk[dy * 3 + dx];
            }
        }
        float s = g1[k] * rsqrtf(v1[k] + EPS);
        tile[ty + jj * 8][tx] = fmaxf((acc - m1[k]) * s + b1[k], 0.f);
    }
    __syncthreads();
#pragma unroll
    for (int jj = 0; jj < 4; jj++) {
        int p = pbase + ty + jj * 8;
        xcat[(size_t)p * 768 + 512 + kbase + tx] = f2bf(tile[tx][ty + jj * 8]);
    }
}

// ---------------- transpose x (512 ch only) -> xcat[.,0:512] bf16 ----------------
__global__ void transpose_kernel(const float* __restrict__ x,
                                 unsigned short* __restrict__ xcat) {
    __shared__ float tile[32][33];
    int tx = threadIdx.x & 31, ty = threadIdx.x >> 5;
    int pbase = blockIdx.x * 32, cbase = blockIdx.y * 32;
#pragma unroll
    for (int j = 0; j < 4; j++) {
        int c = cbase + ty + j * 8;
        tile[ty + j * 8][tx] = x[(size_t)c * NPIX + pbase + tx];
    }
    __syncthreads();
#pragma unroll
    for (int j = 0; j < 4; j++) {
        int p = pbase + ty + j * 8;
        xcat[(size_t)p * 768 + cbase + tx] = f2bf(tile[tx][ty + j * 8]);
    }
}

// ---- conv1 (1x1, K=768): distance-2 pipeline, A triple-buf LDS, B reg-dbuf ----
// grid (8, 160); block 64; wave tile 160 px x 64 co
__global__ __launch_bounds__(64, 1) void conv1_mfma(const unsigned short* __restrict__ xcat,
        const unsigned short* __restrict__ wAf,
        const float* __restrict__ scale2, const float* __restrict__ shift2,
        unsigned short* __restrict__ hpad) {
    __shared__ unsigned short Al[3][640 * 8];
    int g = blockIdx.x, y = blockIdx.y, co0 = g * 64;
    int lane = threadIdx.x;
    int l31 = lane & 31, q = lane >> 5;
    f32x16 acc[5][2] = {};

    int aoff[10];
#pragma unroll
    for (int r = 0; r < 10; r++) {
        int gg = r * 64 + lane;
        int px = gg >> 2, jg = (gg & 3) ^ ((px >> 1) & 3);
        aoff[r] = px * 768 + jg * 8;
    }
    int raoff[2];
#pragma unroll
    for (int s = 0; s < 2; s++)
        raoff[s] = l31 * 64 + (((s * 2 + q) ^ ((l31 >> 1) & 3)) << 4);
    const unsigned short* arow = xcat + (size_t)y * HW * 768;
    const s16x8* bbase = (const s16x8*)wAf + ((size_t)g * 24) * 256 + lane;

    auto stageA = [&](int ph, int buf) {
        int kc = ph * 32;
        unsigned short* An = Al[buf];
#pragma unroll
        for (int r = 0; r < 10; r++) ldg_lds16(arow + kc + aoff[r], &An[r * 512]);
    };
    s16x8 bfb[2][2][2];
    auto loadB = [&](int ph, int sel) {
#pragma unroll
        for (int j = 0; j < 2; j++)
#pragma unroll
            for (int s = 0; s < 2; s++)
                bfb[sel][j][s] = bbase[(size_t)ph * 256 + (j * 2 + s) * 64];
    };

    stageA(0, 0); loadB(0, 0);
    stageA(1, 1); loadB(1, 1);
    for (int ph = 0; ph < 24; ph++) {
        const unsigned short* Ar = Al[ph % 3];
        if (ph == 23) { WAIT_VM0(); } else { WAIT_VM14(); }  // A(ph),B(ph) landed; (ph+1) in flight
        s16x8 af[5][2];
#pragma unroll
        for (int s = 0; s < 2; s++)
#pragma unroll
            for (int i = 0; i < 5; i++)
                af[i][s] = *(const s16x8*)((const char*)Ar + i * 2048 + raoff[s]);
        if (ph < 22) stageA(ph + 2, (ph + 2) % 3);
        int sel = ph & 1;
#pragma unroll
        for (int s = 0; s < 2; s++)
#pragma unroll
            for (int i = 0; i < 5; i++)
#pragma unroll
                for (int j = 0; j < 2; j++)
                    acc[i][j] = __builtin_amdgcn_mfma_f32_32x32x16_bf16(af[i][s], bfb[sel][j][s], acc[i][j], 0, 0, 0);
        if (ph < 22) loadB(ph + 2, sel);   // after last use of bfb[sel]
    }
    // epilogue: C/D layout col=lane&31, row=(reg&3)+8*(reg>>2)+4*q
#pragma unroll
    for (int j = 0; j < 2; j++) {
        int co = co0 + j * 32 + l31;
        float s2 = scale2[co], sh = shift2[co];
#pragma unroll
        for (int i = 0; i < 5; i++) {
#pragma unroll
            for (int rg = 0; rg < 4; rg++) {
#pragma unroll
                for (int t = 0; t < 4; t++) {
                    int px = i * 32 + t + rg * 8 + q * 4;
                    size_t pp = (size_t)(y + 1) * PW + px + 1;
                    hpad[pp * 512 + co] = f2bf(acc[i][j][rg * 4 + t] * s2 + sh);
                }
            }
        }
    }
}

// ---- conv3 (3x3, K=4608): distance-2 pipeline, A triple-buf LDS, B reg-dbuf ----
// grid (8, 160); block 64; wave tile 160 px x 64 co
__global__ __launch_bounds__(64, 1) void conv3_mfma(const unsigned short* __restrict__ hpad,
        const unsigned short* __restrict__ w3f,
        const float* __restrict__ bias, float* __restrict__ out) {
    __shared__ unsigned short Al[3][648 * 8];
    int g = blockIdx.x, y = blockIdx.y, co0 = g * 64;
    int lane = threadIdx.x;
    int l31 = lane & 31, q = lane >> 5;
    f32x16 acc[5][2] = {};

    int aoff[11];
#pragma unroll
    for (int r = 0; r < 11; r++) {
        int gg = r * 64 + lane;
        int px = gg >> 2, jg = (gg & 3) ^ ((px >> 1) & 3);
        aoff[r] = px * 512 + jg * 8;
    }
    int raoff[3][2];
#pragma unroll
    for (int dx = 0; dx < 3; dx++)
#pragma unroll
        for (int s = 0; s < 2; s++) {
            int m = l31 + dx;
            raoff[dx][s] = m * 64 + ((((s * 2 + q)) ^ ((m >> 1) & 3)) << 4);
        }
    const s16x8* bbase = (const s16x8*)w3f + ((size_t)g * 48) * 768 + lane;

    auto stageA = [&](int ph, int buf) {
        int dy = ph >> 4, kc = (ph & 15) * 32;
        const unsigned short* ab = hpad + ((size_t)(y + dy) * PW) * 512 + kc;
        unsigned short* An = Al[buf];
#pragma unroll
        for (int r = 0; r < 10; r++) ldg_lds16(ab + aoff[r], &An[r * 512]);
        if (lane < 8)                ldg_lds16(ab + aoff[10], &An[10 * 512]);
    };
    s16x8 bfb[2][3][2][2];
    auto loadB = [&](int ph, int sel) {
#pragma unroll
        for (int dx = 0; dx < 3; dx++)
#pragma unroll
            for (int j = 0; j < 2; j++)
#pragma unroll
                for (int s = 0; s < 2; s++)
                    bfb[sel][dx][j][s] = bbase[(size_t)ph * 768 + (dx * 4 + j * 2 + s) * 64];
    };

    stageA(0, 0); loadB(0, 0);
    stageA(1, 1); loadB(1, 1);
    for (int ph = 0; ph < 48; ph++) {
        const unsigned short* Ar = Al[ph % 3];
        if (ph == 47) { WAIT_VM0(); } else { WAIT_VM23(); }  // A(ph),B(ph) landed; (ph+1) in flight
        int sel = ph & 1;
#pragma unroll
        for (int dx = 0; dx < 3; dx++) {
            s16x8 af[5][2];
#pragma unroll
            for (int s = 0; s < 2; s++)
#pragma unroll
                for (int i = 0; i < 5; i++)
                    af[i][s] = *(const s16x8*)((const char*)Ar + i * 2048 + raoff[dx][s]);
            if (dx == 0 && ph < 46) stageA(ph + 2, (ph + 2) % 3);
#pragma unroll
            for (int s = 0; s < 2; s++)
#pragma unroll
                for (int i = 0; i < 5; i++)
#pragma unroll
                    for (int j = 0; j < 2; j++)
                        acc[i][j] = __builtin_amdgcn_mfma_f32_32x32x16_bf16(af[i][s], bfb[sel][dx][j][s], acc[i][j], 0, 0, 0);
        }
        if (ph < 46) loadB(ph + 2, sel);   // after last use of bfb[sel]
    }
    // epilogue: float4 stores
#pragma unroll
    for (int j = 0; j < 2; j++) {
        int co = co0 + j * 32 + l31;
        float b = bias[co];
        float* op = out + (size_t)co * NPIX + y * HW;
#pragma unroll
        for (int i = 0; i < 5; i++) {
#pragma unroll
            for (int rg = 0; rg < 4; rg++) {
                int px = i * 32 + rg * 8 + q * 4;
                float4 v;
                v.x = fmaxf(acc[i][j][rg * 4 + 0] + b, 0.f);
                v.y = fmaxf(acc[i][j][rg * 4 + 1] + b, 0.f);
                v.z = fmaxf(acc[i][j][rg * 4 + 2] + b, 0.f);
                v.w = fmaxf(acc[i][j][rg * 4 + 3] + b, 0.f);
                *(float4*)&op[px] = v;
            }
        }
    }
}

extern "C" void kernel_launch(void* const* d_in, const int* in_sizes, int n_in,
                              void* d_out, int out_size, void* d_ws, size_t ws_size,
                              hipStream_t stream) {
    const float* x      = (const float*)d_in[0];
    const float* w_fc1  = (const float*)d_in[1];
    const float* w_fc2  = (const float*)d_in[2];
    const float* w_ch   = (const float*)d_in[3];
    const float* bn1_g  = (const float*)d_in[4];
    const float* bn1_b  = (const float*)d_in[5];
    const float* bn1_m  = (const float*)d_in[6];
    const float* bn1_v  = (const float*)d_in[7];
    const float* w_dc1  = (const float*)d_in[8];
    const float* b_dc1  = (const float*)d_in[9];
    const float* bn2_g  = (const float*)d_in[10];
    const float* bn2_b  = (const float*)d_in[11];
    const float* bn2_m  = (const float*)d_in[12];
    const float* bn2_v  = (const float*)d_in[13];
    const float* w_dc2  = (const float*)d_in[14];
    const float* b_dc2  = (const float*)d_in[15];
    float* out = (float*)d_out;

    char* ws = (char*)d_ws;
    float* avg    = (float*)(ws + 0);
    float* mx     = (float*)(ws + 2048);
    float* scales = (float*)(ws + 4096);
    int*   idx    = (int*)  (ws + 6144);
    int*   pos    = (int*)  (ws + 7168);
    float* scale2 = (float*)(ws + 9216);
    float* shift2 = (float*)(ws + 11264);
    unsigned short* wAf  = (unsigned short*)(ws + 16384);              // 8*24*2048*2 = 786432
    unsigned short* w3f  = (unsigned short*)(ws + 802816);             // 384*6144*2 = 4718592
    unsigned short* xcat = (unsigned short*)(ws + 31735808);           // 25600*768*2 = 39321600
    unsigned short* hpad = (unsigned short*)(ws + 71057408);           // 162*162*512*2 = 26873856

    reduce_kernel<<<C, 256, 0, stream>>>(x, avg, mx);
    mlp_select_kernel<<<1, C, 0, stream>>>(avg, mx, w_fc1, w_fc2, scales, idx, pos);
    prep_kernel<<<738, 256, 0, stream>>>(w_dc2, w3f, w_dc1, scales, pos, wAf, hpad,
                                         b_dc1, bn2_g, bn2_b, bn2_m, bn2_v, scale2, shift2);
    dw_t_kernel<<<dim3(800, 8), 256, 0, stream>>>(x, idx, w_ch, bn1_g, bn1_b, bn1_m, bn1_v, xcat);
    transpose_kernel<<<dim3(800, 16), 256, 0, stream>>>(x, xcat);
    conv1_mfma<<<dim3(8, HW), 64, 0, stream>>>(xcat, wAf, scale2, shift2, hpad);
    conv3_mfma<<<dim3(8, HW), 64, 0, stream>>>(hpad, w3f, b_dc2, out);
}

// Round 11
// 475.765 us; speedup vs baseline: 1.6719x; 1.6719x over previous
//
#include <hip/hip_runtime.h>
#include <math.h>

#define C 512
#define K 256
#define HW 160
#define NPIX (HW*HW)   // 25600
#define PW 162
#define EPS 1e-5f

typedef __attribute__((ext_vector_type(8))) short s16x8;
typedef __attribute__((ext_vector_type(16))) float f32x16;

__device__ __forceinline__ unsigned short f2bf(float f) {
    unsigned int u = __float_as_uint(f);
    u += 0x7fffu + ((u >> 16) & 1u);
    return (unsigned short)(u >> 16);
}

// async global->LDS 16B: LDS dest = wave-uniform base + lane*16
__device__ __forceinline__ void ldg_lds16(const void* g, void* l) {
    __builtin_amdgcn_global_load_lds((const __attribute__((address_space(1))) unsigned int*)g,
                                     (__attribute__((address_space(3))) unsigned int*)l, 16, 0, 0);
}

#define WAIT_VM0()   asm volatile("s_waitcnt vmcnt(0)" ::: "memory")

// ---------------- per-channel mean & max ----------------
__global__ void reduce_kernel(const float* __restrict__ x,
                              float* __restrict__ avg, float* __restrict__ mx) {
    int c = blockIdx.x;
    const float4* xc = (const float4*)(x + (size_t)c * NPIX);
    float s = 0.f, m = -INFINITY;
    for (int p = threadIdx.x; p < NPIX / 4; p += 256) {
        float4 v = xc[p];
        s += v.x + v.y + v.z + v.w;
        m = fmaxf(m, fmaxf(fmaxf(v.x, v.y), fmaxf(v.z, v.w)));
    }
    __shared__ float ss[256], sm[256];
    ss[threadIdx.x] = s; sm[threadIdx.x] = m;
    __syncthreads();
    for (int o = 128; o > 0; o >>= 1) {
        if (threadIdx.x < o) {
            ss[threadIdx.x] += ss[threadIdx.x + o];
            sm[threadIdx.x] = fmaxf(sm[threadIdx.x], sm[threadIdx.x + o]);
        }
        __syncthreads();
    }
    if (threadIdx.x == 0) {
        avg[c] = ss[0] / (float)NPIX;
        mx[c]  = sm[0];
    }
}

// ---------------- fc1: 256 blocks, one wave each ----------------
__global__ void fc1_kernel(const float* __restrict__ avg, const float* __restrict__ mx,
                           const float* __restrict__ w_fc1, float* __restrict__ h) {
    int t = blockIdx.x, lane = threadIdx.x;
    const float* wr = w_fc1 + (size_t)t * C;
    float pa = 0.f, pm = 0.f;
    for (int c = lane; c < C; c += 64) {
        float w = wr[c];
        pa += avg[c] * w;
        pm += mx[c] * w;
    }
    for (int o = 32; o > 0; o >>= 1) {
        pa += __shfl_down(pa, o);
        pm += __shfl_down(pm, o);
    }
    if (lane == 0) h[t] = fmaxf(pa, 0.f) + fmaxf(pm, 0.f);
}

// ---------------- fc2 + sigmoid: 512 blocks, one wave each ----------------
__global__ void fc2_kernel(const float* __restrict__ h, const float* __restrict__ w_fc2,
                           float* __restrict__ scales) {
    int c = blockIdx.x, lane = threadIdx.x;
    const float* wr = w_fc2 + (size_t)c * K;
    float o = 0.f;
    for (int k = lane; k < K; k += 64) o += h[k] * wr[k];
    for (int s = 32; s > 0; s >>= 1) o += __shfl_down(o, s);
    if (lane == 0) scales[c] = 1.f / (1.f + expf(-o));
}

// ---------------- top-K selection (tiny, 1 block) ----------------
__global__ void select_kernel(const float* __restrict__ scales,
                              int* __restrict__ idx, int* __restrict__ pos) {
    __shared__ float s_scales[C];
    __shared__ int s_sel[C];
    int t = threadIdx.x;
    s_scales[t] = scales[t];
    __syncthreads();
    {
        float v = s_scales[t];
        int rank = 0;
        for (int i = 0; i < C; i++) {
            float u = s_scales[i];
            rank += (u > v) || (u == v && i < t);
        }
        s_sel[t] = (rank < K) ? 1 : 0;
    }
    __syncthreads();
    {
        int p = 0;
        for (int i = 0; i < t; i++) p += s_sel[i];
        if (s_sel[t]) { idx[p] = t; pos[t] = p; }
        else pos[t] = -1;
    }
}

// ---- fused prep: w3 repack (LDS-staged, coalesced) + wA + zero border + affine ----
__global__ void prep_kernel(const float* __restrict__ w_dc2, unsigned short* __restrict__ w3,
                            const float* __restrict__ w_dc1, const float* __restrict__ scales,
                            const int* __restrict__ pos, unsigned short* __restrict__ wA,
                            unsigned short* __restrict__ hpad,
                            const float* __restrict__ b_dc1,
                            const float* __restrict__ g2, const float* __restrict__ b2,
                            const float* __restrict__ m2, const float* __restrict__ v2,
                            float* __restrict__ scale2, float* __restrict__ shift2) {
    __shared__ unsigned short lw[4608];
    int b = blockIdx.x;
    if (b < 512) {                       // w3: [co][ci][t] -> [t][co][ci], LDS staged
        int co = b;
        const float* src = w_dc2 + (size_t)co * 4608;
        for (int u = threadIdx.x; u < 4608; u += 256)
            lw[u] = f2bf(src[u]);                        // coalesced read
        __syncthreads();
        for (int u = threadIdx.x; u < 4608; u += 256) {
            int t = u >> 9, ci = u & 511;
            w3[((size_t)t * 512 + co) * 512 + ci] = lw[ci * 9 + t];  // coalesced write
        }
    } else if (b < 1024) {               // wA combined 1x1 weight
        int co = b - 512;
        const float* wr = w_dc1 + (size_t)co * 1024;
        for (int c = threadIdx.x; c < 768; c += 256) {
            float v;
            if (c < 512) {
                v = wr[c] * scales[c];
                int pp = pos[c];
                if (pp >= 0) v += wr[512 + pp];
            } else {
                v = wr[768 + (c - 512)];
            }
            wA[(size_t)co * 768 + c] = f2bf(v);
        }
    } else if (b < 1185) {               // zero hpad border
        int t = (b - 1024) * 256 + threadIdx.x;
        int pix = t >> 6;
        int p;
        if (pix < 162)      p = pix;
        else if (pix < 324) p = 161 * PW + (pix - 162);
        else {
            int r = pix - 324;
            p = (1 + (r >> 1)) * PW + ((r & 1) ? 161 : 0);
        }
        *(uint4*)&hpad[(size_t)p * 512 + (t & 63) * 8] = make_uint4(0u, 0u, 0u, 0u);
    } else {                             // affine (BN2 + bias fold)
        for (int c = threadIdx.x; c < C; c += 256) {
            float s = g2[c] * rsqrtf(v2[c] + EPS);
            scale2[c] = s;
            shift2[c] = (b_dc1[c] - m2[c]) * s + b2[c];
        }
    }
}

// ---------------- dw 3x3 + BN1 + ReLU, written transposed into xcat[.,512+k] ----
__global__ void dw_t_kernel(const float* __restrict__ x,
                            const int* __restrict__ idx,
                            const float* __restrict__ wch,
                            const float* __restrict__ g1, const float* __restrict__ b1,
                            const float* __restrict__ m1, const float* __restrict__ v1,
                            unsigned short* __restrict__ xcat) {
    __shared__ float tile[32][33];
    int tx = threadIdx.x & 31, ty = threadIdx.x >> 5;
    int pbase = blockIdx.x * 32, kbase = blockIdx.y * 32;
    int y = pbase / HW, x0 = pbase % HW;
    int px = x0 + tx;
#pragma unroll
    for (int jj = 0; jj < 4; jj++) {
        int k = kbase + ty + jj * 8;
        int c = idx[k];
        const float* xc = x + (size_t)c * NPIX;
        const float* wk = wch + k * 9;
        float acc = 0.f;
#pragma unroll
        for (int dy = 0; dy < 3; dy++) {
            int yy = y + dy - 1;
            if (yy < 0 || yy >= HW) continue;
#pragma unroll
            for (int dx = 0; dx < 3; dx++) {
                int xv = px + dx - 1;
                if (xv < 0 || xv >= HW) continue;
                acc += xc[yy * HW + xv] * wk[dy * 3 + dx];
            }
        }
        float s = g1[k] * rsqrtf(v1[k] + EPS);
        tile[ty + jj * 8][tx] = fmaxf((acc - m1[k]) * s + b1[k], 0.f);
    }
    __syncthreads();
#pragma unroll
    for (int jj = 0; jj < 4; jj++) {
        int p = pbase + ty + jj * 8;
        xcat[(size_t)p * 768 + 512 + kbase + tx] = f2bf(tile[tx][ty + jj * 8]);
    }
}

// ---------------- transpose x (512 ch only) -> xcat[.,0:512] bf16 ----------------
__global__ void transpose_kernel(const float* __restrict__ x,
                                 unsigned short* __restrict__ xcat) {
    __shared__ float tile[32][33];
    int tx = threadIdx.x & 31, ty = threadIdx.x >> 5;
    int pbase = blockIdx.x * 32, cbase = blockIdx.y * 32;
#pragma unroll
    for (int j = 0; j < 4; j++) {
        int c = cbase + ty + j * 8;
        tile[ty + j * 8][tx] = x[(size_t)c * NPIX + pbase + tx];
    }
    __syncthreads();
#pragma unroll
    for (int j = 0; j < 4; j++) {
        int p = pbase + ty + j * 8;
        xcat[(size_t)p * 768 + cbase + tx] = f2bf(tile[tx][ty + j * 8]);
    }
}

// ---------------- conv1 (1x1, K=768): 1-wave, dbuf, early-stage pipeline ----------------
// grid (160, 8); block 64; wave tile 160 px x 64 co
__global__ __launch_bounds__(64, 1) void conv1_mfma(const unsigned short* __restrict__ xcat,
        const unsigned short* __restrict__ wA,
        const float* __restrict__ scale2, const float* __restrict__ shift2,
        unsigned short* __restrict__ hpad) {
    __shared__ unsigned short Al[2][640 * 8];
    __shared__ unsigned short Bl[2][256 * 8];
    int y = blockIdx.x, co0 = blockIdx.y * 64;
    int lane = threadIdx.x;
    int l31 = lane & 31, q = lane >> 5;
    f32x16 acc[5][2] = {};

    int aoff[10], boff[4];
#pragma unroll
    for (int r = 0; r < 10; r++) {
        int g = r * 64 + lane;
        int px = g >> 2, jg = (g & 3) ^ ((px >> 1) & 3);
        aoff[r] = px * 768 + jg * 8;
    }
#pragma unroll
    for (int r = 0; r < 4; r++) {
        int g = r * 64 + lane;
        int co = g >> 2, jg = (g & 3) ^ ((co >> 1) & 3);
        boff[r] = co * 768 + jg * 8;
    }
    int raoff[2];
#pragma unroll
    for (int s = 0; s < 2; s++)
        raoff[s] = l31 * 64 + (((s * 2 + q) ^ ((l31 >> 1) & 3)) << 4);
    const unsigned short* arow = xcat + (size_t)y * HW * 768;
    const unsigned short* brow = wA + (size_t)co0 * 768;

    auto stage = [&](int ph, int buf) {
        int kc = ph * 32;
        unsigned short* An = Al[buf];
        unsigned short* Bn = Bl[buf];
#pragma unroll
        for (int r = 0; r < 10; r++) ldg_lds16(arow + kc + aoff[r], &An[r * 512]);
#pragma unroll
        for (int r = 0; r < 4; r++)  ldg_lds16(brow + kc + boff[r], &Bn[r * 512]);
    };

    stage(0, 0);
    for (int ph = 0; ph < 24; ph++) {
        const unsigned short* Ar = Al[ph & 1];
        const unsigned short* Br = Bl[ph & 1];
        WAIT_VM0();                          // this buffer's DMA landed
        if (ph < 23) stage(ph + 1, (ph + 1) & 1);   // max lead time, other buffer
        s16x8 af[5][2], bf[2][2];
#pragma unroll
        for (int s = 0; s < 2; s++) {
#pragma unroll
            for (int i = 0; i < 5; i++)
                af[i][s] = *(const s16x8*)((const char*)Ar + i * 2048 + raoff[s]);
#pragma unroll
            for (int j = 0; j < 2; j++)
                bf[j][s] = *(const s16x8*)((const char*)Br + j * 2048 + raoff[s]);
        }
#pragma unroll
        for (int s = 0; s < 2; s++)
#pragma unroll
            for (int i = 0; i < 5; i++)
#pragma unroll
                for (int j = 0; j < 2; j++)
                    acc[i][j] = __builtin_amdgcn_mfma_f32_32x32x16_bf16(af[i][s], bf[j][s], acc[i][j], 0, 0, 0);
    }
    // epilogue: C/D layout col=lane&31, row=(reg&3)+8*(reg>>2)+4*q
#pragma unroll
    for (int j = 0; j < 2; j++) {
        int co = co0 + j * 32 + l31;
        float s2 = scale2[co], sh = shift2[co];
#pragma unroll
        for (int i = 0; i < 5; i++) {
#pragma unroll
            for (int rg = 0; rg < 4; rg++) {
#pragma unroll
                for (int t = 0; t < 4; t++) {
                    int px = i * 32 + t + rg * 8 + q * 4;
                    size_t pp = (size_t)(y + 1) * PW + px + 1;
                    hpad[pp * 512 + co] = f2bf(acc[i][j][rg * 4 + t] * s2 + sh);
                }
            }
        }
    }
}

// ---------------- conv3 (3x3, K=4608): 1-wave, dbuf, early-stage pipeline ----------------
// grid (160, 8); block 64; wave tile 160 px x 64 co
__global__ __launch_bounds__(64, 1) void conv3_mfma(const unsigned short* __restrict__ hpad,
        const unsigned short* __restrict__ w3,
        const float* __restrict__ bias, float* __restrict__ out) {
    __shared__ unsigned short Al[2][648 * 8];   // 162 px x 32 ch
    __shared__ unsigned short Bl[2][768 * 8];   // 3 dx x 64 co x 32 ch
    int y = blockIdx.x, co0 = blockIdx.y * 64;
    int lane = threadIdx.x;
    int l31 = lane & 31, q = lane >> 5;
    f32x16 acc[5][2] = {};

    int aoff[11], boff[12];
#pragma unroll
    for (int r = 0; r < 11; r++) {
        int g = r * 64 + lane;
        int px = g >> 2, jg = (g & 3) ^ ((px >> 1) & 3);
        aoff[r] = px * 512 + jg * 8;
    }
#pragma unroll
    for (int r = 0; r < 12; r++) {
        int g = r * 64 + lane;
        int tt = g >> 8, co = (g >> 2) & 63, jg = (g & 3) ^ ((co >> 1) & 3);
        boff[r] = (tt * 512 + co) * 512 + jg * 8;
    }
    int raoff[3][2], rboff[2];
#pragma unroll
    for (int dx = 0; dx < 3; dx++)
#pragma unroll
        for (int s = 0; s < 2; s++) {
            int m = l31 + dx;
            raoff[dx][s] = m * 64 + ((((s * 2 + q)) ^ ((m >> 1) & 3)) << 4);
        }
#pragma unroll
    for (int s = 0; s < 2; s++)
        rboff[s] = l31 * 64 + (((s * 2 + q) ^ ((l31 >> 1) & 3)) << 4);

    auto stage = [&](int ph, int buf) {
        int dy = ph >> 4, kc = (ph & 15) * 32;
        const unsigned short* ab = hpad + ((size_t)(y + dy) * PW) * 512 + kc;
        unsigned short* An = Al[buf];
#pragma unroll
        for (int r = 0; r < 10; r++) ldg_lds16(ab + aoff[r], &An[r * 512]);
        if (lane < 8)                ldg_lds16(ab + aoff[10], &An[10 * 512]);
        const unsigned short* bb = w3 + ((size_t)(dy * 3) * 512 + co0) * 512 + kc;
        unsigned short* Bn = Bl[buf];
#pragma unroll
        for (int r = 0; r < 12; r++) ldg_lds16(bb + boff[r], &Bn[r * 512]);
    };

    stage(0, 0);
    for (int ph = 0; ph < 48; ph++) {
        const unsigned short* Ar = Al[ph & 1];
        const unsigned short* Br = Bl[ph & 1];
        WAIT_VM0();                          // this buffer's DMA landed
        if (ph < 47) stage(ph + 1, (ph + 1) & 1);   // issued first: full phase of lead time
        // dx-interleaved reads+MFMA; compiler's fine-grained lgkmcnt overlaps the pipes
#pragma unroll
        for (int dx = 0; dx < 3; dx++) {
            s16x8 af[5][2], bf[2][2];
#pragma unroll
            for (int s = 0; s < 2; s++) {
#pragma unroll
                for (int i = 0; i < 5; i++)
                    af[i][s] = *(const s16x8*)((const char*)Ar + i * 2048 + raoff[dx][s]);
#pragma unroll
                for (int j = 0; j < 2; j++)
                    bf[j][s] = *(const s16x8*)((const char*)Br + dx * 4096 + j * 2048 + rboff[s]);
            }
#pragma unroll
            for (int s = 0; s < 2; s++)
#pragma unroll
                for (int i = 0; i < 5; i++)
#pragma unroll
                    for (int j = 0; j < 2; j++)
                        acc[i][j] = __builtin_amdgcn_mfma_f32_32x32x16_bf16(af[i][s], bf[j][s], acc[i][j], 0, 0, 0);
        }
    }
    // epilogue: float4 stores
#pragma unroll
    for (int j = 0; j < 2; j++) {
        int co = co0 + j * 32 + l31;
        float b = bias[co];
        float* op = out + (size_t)co * NPIX + y * HW;
#pragma unroll
        for (int i = 0; i < 5; i++) {
#pragma unroll
            for (int rg = 0; rg < 4; rg++) {
                int px = i * 32 + rg * 8 + q * 4;
                float4 v;
                v.x = fmaxf(acc[i][j][rg * 4 + 0] + b, 0.f);
                v.y = fmaxf(acc[i][j][rg * 4 + 1] + b, 0.f);
                v.z = fmaxf(acc[i][j][rg * 4 + 2] + b, 0.f);
                v.w = fmaxf(acc[i][j][rg * 4 + 3] + b, 0.f);
                *(float4*)&op[px] = v;
            }
        }
    }
}

extern "C" void kernel_launch(void* const* d_in, const int* in_sizes, int n_in,
                              void* d_out, int out_size, void* d_ws, size_t ws_size,
                              hipStream_t stream) {
    const float* x      = (const float*)d_in[0];
    const float* w_fc1  = (const float*)d_in[1];
    const float* w_fc2  = (const float*)d_in[2];
    const float* w_ch   = (const float*)d_in[3];
    const float* bn1_g  = (const float*)d_in[4];
    const float* bn1_b  = (const float*)d_in[5];
    const float* bn1_m  = (const float*)d_in[6];
    const float* bn1_v  = (const float*)d_in[7];
    const float* w_dc1  = (const float*)d_in[8];
    const float* b_dc1  = (const float*)d_in[9];
    const float* bn2_g  = (const float*)d_in[10];
    const float* bn2_b  = (const float*)d_in[11];
    const float* bn2_m  = (const float*)d_in[12];
    const float* bn2_v  = (const float*)d_in[13];
    const float* w_dc2  = (const float*)d_in[14];
    const float* b_dc2  = (const float*)d_in[15];
    float* out = (float*)d_out;

    char* ws = (char*)d_ws;
    float* avg    = (float*)(ws + 0);
    float* mx     = (float*)(ws + 2048);
    float* scales = (float*)(ws + 4096);
    int*   idx    = (int*)  (ws + 6144);
    int*   pos    = (int*)  (ws + 7168);
    float* scale2 = (float*)(ws + 9216);
    float* shift2 = (float*)(ws + 11264);
    float* hbuf   = (float*)(ws + 13312);
    unsigned short* wA   = (unsigned short*)(ws + 16384);              // 512*768*2  = 786432
    unsigned short* w3   = (unsigned short*)(ws + 802816);             // 9*512*512*2 = 4718592
    unsigned short* xcat = (unsigned short*)(ws + 31735808);           // 25600*768*2 = 39321600
    unsigned short* hpad = (unsigned short*)(ws + 71057408);           // 162*162*512*2 = 26873856

    reduce_kernel<<<C, 256, 0, stream>>>(x, avg, mx);
    fc1_kernel<<<K, 64, 0, stream>>>(avg, mx, w_fc1, hbuf);
    fc2_kernel<<<C, 64, 0, stream>>>(hbuf, w_fc2, scales);
    select_kernel<<<1, C, 0, stream>>>(scales, idx, pos);
    prep_kernel<<<1186, 256, 0, stream>>>(w_dc2, w3, w_dc1, scales, pos, wA, hpad,
                                          b_dc1, bn2_g, bn2_b, bn2_m, bn2_v, scale2, shift2);
    dw_t_kernel<<<dim3(800, 8), 256, 0, stream>>>(x, idx, w_ch, bn1_g, bn1_b, bn1_m, bn1_v, xcat);
    transpose_kernel<<<dim3(800, 16), 256, 0, stream>>>(x, xcat);
    conv1_mfma<<<dim3(HW, 8), 64, 0, stream>>>(xcat, wA, scale2, shift2, hpad);
    conv3_mfma<<<dim3(HW, 8), 64, 0, stream>>>(hpad, w3, b_dc2, out);
}